// Round 3
// baseline (192.012 us; speedup 1.0000x reference)
//
#include <hip/hip_runtime.h>

// Problem constants
#define BB 4
#define SS 2048
#define EE 640
#define NHH 10
#define DHH 64
#define MTOK 8192   // BB*SS
#define E33 1920

#define LDST 72     // attn LDS row stride (elements): 144B, 16B-aligned

typedef float f32x4 __attribute__((ext_vector_type(4)));
typedef __bf16 bf16x8 __attribute__((ext_vector_type(8)));
typedef unsigned short u16;
typedef u16 u16x4 __attribute__((ext_vector_type(4)));

#define QSCALE 0.1803368801f   // 0.125 * log2(e): scores exit QK^T in log2 domain

#if __has_builtin(__builtin_amdgcn_exp2f)
#define EXP2 __builtin_amdgcn_exp2f
#else
#define EXP2 exp2f
#endif

__device__ inline u16 f2bf(float f) {
  unsigned u = __builtin_bit_cast(unsigned, f);
  u += 0x7fffu + ((u >> 16) & 1u);   // round-to-nearest-even
  return (u16)(u >> 16);
}

// pack two floats to bf16 pair (round-half-up) in 3 VALU ops
__device__ inline unsigned pk2(float lo, float hi) {
  unsigned a = __builtin_bit_cast(unsigned, lo) + 0x8000u;
  unsigned b = __builtin_bit_cast(unsigned, hi) + 0x8000u;
  return __builtin_amdgcn_perm(b, a, 0x07060302u);  // {b.hi16, a.hi16}
}

// async global->LDS, 16B per lane; lds ptr must be wave-uniform (lane scatters i*16)
__device__ inline void gll16(const u16* g, u16* l) {
  __builtin_amdgcn_global_load_lds(
      (const __attribute__((address_space(1))) unsigned*)g,
      (__attribute__((address_space(3))) unsigned*)l, 16, 0, 0);
}

// ---------------------------------------------------------------- convert (fused)
__global__ void convert_all(const float* __restrict__ x, const float* __restrict__ wqkv,
                            const float* __restrict__ wproj, u16* __restrict__ xb,
                            u16* __restrict__ wqkvb, u16* __restrict__ wprojb) {
  int i = blockIdx.x * blockDim.x + threadIdx.x;   // < 1720320 exactly
  const float* src; u16* dst; int off;
  if (i < 1310720)      { src = x;     dst = xb;     off = i; }
  else if (i < 1617920) { src = wqkv;  dst = wqkvb;  off = i - 1310720; }
  else                  { src = wproj; dst = wprojb; off = i - 1617920; }
  float4 v = ((const float4*)src)[off];
  u16x4 o = { f2bf(v.x), f2bf(v.y), f2bf(v.z), f2bf(v.w) };
  ((u16x4*)dst)[off] = o;
}

// ---------------------------------------------------------------- QKV GEMM (m97-style)
// C[8192,1920] = A[8192,640]*Bt[1920,640]^T. LDS layout [r/8][kc][r%8]x16B:
// gll lane-order == layout, ds_read_b128 fragments conflict-min, global reads 128B rows.
// Q stored transposed+pre-scaled by QSCALE; V transposed; K row-major.
__global__ __launch_bounds__(256) void gemm_qkv(
    const u16* __restrict__ A, const u16* __restrict__ Bt,
    u16* __restrict__ qT, u16* __restrict__ kb, u16* __restrict__ vt) {
  __shared__ __align__(16) u16 As[128 * 64];
  __shared__ __align__(16) u16 Bs[128 * 64];
  const int t = threadIdx.x, w = t >> 6, lane = t & 63;
  const int n16 = lane & 15, quad = lane >> 4;
  const int wm = w >> 1, wn = w & 1;
  const int m0 = blockIdx.y * 128, n0 = blockIdx.x * 128;
  const int mr = lane & 7, kc8 = (lane >> 3) * 8;

  const u16* gA = A + (m0 + w * 32 + mr) * 640 + kc8;
  const u16* gB = Bt + (n0 + w * 32 + mr) * 640 + kc8;
  u16* lA = &As[w * 4 * 512];   // wave-uniform
  u16* lB = &Bs[w * 4 * 512];

  f32x4 acc[4][4];
  for (int i = 0; i < 4; i++)
    for (int j = 0; j < 4; j++) acc[i][j] = f32x4{0.f, 0.f, 0.f, 0.f};

  for (int kt = 0; kt < 10; ++kt) {
    __syncthreads();
    for (int j = 0; j < 4; ++j) {
      gll16(gA + j * 8 * 640 + kt * 64, lA + j * 512);
      gll16(gB + j * 8 * 640 + kt * 64, lB + j * 512);
    }
    __syncthreads();
    for (int ks = 0; ks < 2; ++ks) {
      bf16x8 a[4], b[4];
      for (int mi = 0; mi < 4; mi++) {
        int m = wm * 64 + mi * 16 + n16;
        a[mi] = *(const bf16x8*)&As[(m >> 3) * 512 + (ks * 4 + quad) * 64 + (m & 7) * 8];
      }
      for (int ni = 0; ni < 4; ni++) {
        int n = wn * 64 + ni * 16 + n16;
        b[ni] = *(const bf16x8*)&Bs[(n >> 3) * 512 + (ks * 4 + quad) * 64 + (n & 7) * 8];
      }
      for (int mi = 0; mi < 4; mi++)
        for (int ni = 0; ni < 4; ni++)
          acc[mi][ni] = __builtin_amdgcn_mfma_f32_16x16x32_bf16(a[mi], b[ni], acc[mi][ni], 0, 0, 0);
    }
  }

  const int which = n0 / 640;   // uniform per block (640 % 128 == 0)
  for (int ni = 0; ni < 4; ni++) {
    int col = n0 + wn * 64 + ni * 16 + n16;
    int eh = col - which * 640;
    int h = eh >> 6, d = eh & 63;
    for (int mi = 0; mi < 4; mi++) {
      int tb = m0 + wm * 64 + mi * 16 + quad * 4;   // 4 consecutive tokens
      int b_ = tb >> 11, s_ = tb & 2047;
      int bh = b_ * NHH + h;
      f32x4 c = acc[mi][ni];
      if (which == 0) {
        // Q^T[bh][d][s], pre-scaled into log2 domain
        u16x4 pk = { f2bf(c[0] * QSCALE), f2bf(c[1] * QSCALE),
                     f2bf(c[2] * QSCALE), f2bf(c[3] * QSCALE) };
        *(u16x4*)&qT[(bh * DHH + d) * SS + s_] = pk;
      } else if (which == 2) {
        u16x4 pk = { f2bf(c[0]), f2bf(c[1]), f2bf(c[2]), f2bf(c[3]) };
        *(u16x4*)&vt[(bh * DHH + d) * SS + s_] = pk;
      } else {
        for (int r = 0; r < 4; r++)
          kb[(bh * SS + s_ + r) * DHH + d] = f2bf(c[r]);
      }
    }
  }
}

// ---------------------------------------------------------------- attention
// S^T = K*Q^T: per-lane softmax stats (2 shfls), P^T directly the PV B-operand.
// Q pre-scaled by 0.125*log2e -> softmax in exp2 domain (v_exp_f32 direct).
__global__ __launch_bounds__(256) void attn_kernel(
    const u16* __restrict__ qT, const u16* __restrict__ kb, const u16* __restrict__ vt,
    u16* __restrict__ y) {
  __shared__ __align__(16) u16 Ks[2][64 * LDST];   // K[perm(key)][d]
  __shared__ __align__(16) u16 Vs[2][64 * LDST];   // V^T[d][key]
  const int t = threadIdx.x;
  const int w = t >> 6, lane = t & 63, n16 = lane & 15, quad = lane >> 4;
  const int bh = blockIdx.x;
  const int qt = 31 - blockIdx.y;        // longest blocks first
  const int qb0 = qt * 64;
  const int b_ = bh / NHH, h = bh % NHH;
  const int q_rel = w * 16 + n16;

  // Q B-fragment from Q^T[bh][d][s]: 16 scalar loads, once per block
  bf16x8 aq[2];
  {
    union { bf16x8 v; u16 s[8]; } u0, u1;
    const u16* qp = qT + (bh * DHH) * SS + qb0 + q_rel;
    for (int j = 0; j < 8; j++) u0.s[j] = qp[(quad * 8 + j) * SS];
    for (int j = 0; j < 8; j++) u1.s[j] = qp[(32 + quad * 8 + j) * SS];
    aq[0] = u0.v; aq[1] = u1.v;
  }

  const int c1 = 256 + t;
  const int row0 = t >> 3,  col0 = (t & 7) * 8;
  const int row1 = c1 >> 3, col1 = (c1 & 7) * 8;
  auto perm = [](int k) {   // key -> permuted LDS row for the B-frag key order
    int p = k >> 5, rem = k & 31, qd = rem >> 3, tt = rem & 7;
    return ((p << 1) | (tt >> 2)) * 16 + qd * 4 + (tt & 3);
  };
  const int prow0 = perm(row0), prow1 = perm(row1);

  float4 fk0, fk1, fv0, fv1;
  fk0 = *(const float4*)&kb[(bh * SS + row0) * DHH + col0];
  fk1 = *(const float4*)&kb[(bh * SS + row1) * DHH + col1];
  fv0 = *(const float4*)&vt[(bh * DHH + row0) * SS + col0];
  fv1 = *(const float4*)&vt[(bh * DHH + row1) * SS + col1];
  *(float4*)&Ks[0][prow0 * LDST + col0] = fk0;
  *(float4*)&Ks[0][prow1 * LDST + col1] = fk1;
  *(float4*)&Vs[0][row0 * LDST + col0] = fv0;
  *(float4*)&Vs[0][row1 * LDST + col1] = fv1;

  float m_i = -1e30f, l_i = 0.f;
  f32x4 o[4];
  for (int db = 0; db < 4; db++) o[db] = f32x4{0.f, 0.f, 0.f, 0.f};

  for (int kt = 0; kt <= qt; ++kt) {
    __syncthreads();
    const int cur = kt & 1, nxt = cur ^ 1;
    if (kt < qt) {   // prefetch next tile
      int kk = (kt + 1) * 64;
      fk0 = *(const float4*)&kb[(bh * SS + kk + row0) * DHH + col0];
      fk1 = *(const float4*)&kb[(bh * SS + kk + row1) * DHH + col1];
      fv0 = *(const float4*)&vt[(bh * DHH + row0) * SS + kk + col0];
      fv1 = *(const float4*)&vt[(bh * DHH + row1) * SS + kk + col1];
    }

    // S^T = K * Q^T (already in log2 domain via Q pre-scale)
    f32x4 sc[4];
    for (int nb = 0; nb < 4; nb++) {
      f32x4 c = f32x4{0.f, 0.f, 0.f, 0.f};
      for (int ks = 0; ks < 2; ks++) {
        bf16x8 ak = *(const bf16x8*)&Ks[cur][(nb * 16 + n16) * LDST + ks * 32 + quad * 8];
        c = __builtin_amdgcn_mfma_f32_16x16x32_bf16(ak, aq[ks], c, 0, 0, 0);
      }
      sc[nb] = c;
    }
    if (kt == qt) {   // causal mask, diag tile only (wave-uniform branch)
      for (int nb = 0; nb < 4; nb++)
        for (int r = 0; r < 4; r++) {
          int key = ((nb >> 1) << 5) + quad * 8 + ((nb & 1) << 2) + r;
          if (key > q_rel) sc[nb][r] = -1e30f;
        }
    }

    // online softmax (exp2 domain), per-lane q
    float rm = -1e30f;
    for (int nb = 0; nb < 4; nb++)
      for (int r = 0; r < 4; r++) rm = fmaxf(rm, sc[nb][r]);
    rm = fmaxf(rm, __shfl_xor(rm, 16));
    rm = fmaxf(rm, __shfl_xor(rm, 32));
    float mnew = fmaxf(m_i, rm);
    float alpha = EXP2(m_i - mnew);
    float p[4][4];
    float rs = 0.f;
    for (int nb = 0; nb < 4; nb++)
      for (int r = 0; r < 4; r++) { float pv = EXP2(sc[nb][r] - mnew); p[nb][r] = pv; rs += pv; }
    rs += __shfl_xor(rs, 16);
    rs += __shfl_xor(rs, 32);
    l_i = l_i * alpha + rs;
    m_i = mnew;
    for (int db = 0; db < 4; db++)
      for (int r = 0; r < 4; r++) o[db][r] *= alpha;

    // O^T += V^T * P^T  (P packed via v_perm, already in B layout)
    for (int p2 = 0; p2 < 2; p2++) {
      union { bf16x8 v; unsigned u[4]; } bp;
      bp.u[0] = pk2(p[2 * p2][0],     p[2 * p2][1]);
      bp.u[1] = pk2(p[2 * p2][2],     p[2 * p2][3]);
      bp.u[2] = pk2(p[2 * p2 + 1][0], p[2 * p2 + 1][1]);
      bp.u[3] = pk2(p[2 * p2 + 1][2], p[2 * p2 + 1][3]);
      for (int db = 0; db < 4; db++) {
        bf16x8 av = *(const bf16x8*)&Vs[cur][(db * 16 + n16) * LDST + p2 * 32 + quad * 8];
        o[db] = __builtin_amdgcn_mfma_f32_16x16x32_bf16(av, bp.v, o[db], 0, 0, 0);
      }
    }

    if (kt < qt) {
      *(float4*)&Ks[nxt][prow0 * LDST + col0] = fk0;
      *(float4*)&Ks[nxt][prow1 * LDST + col1] = fk1;
      *(float4*)&Vs[nxt][row0 * LDST + col0] = fv0;
      *(float4*)&Vs[nxt][row1 * LDST + col1] = fv1;
    }
  }

  // epilogue: O^T[d][q] -> y[token][h*64+d]
  const float inv = 1.0f / l_i;
  const int tok = b_ * SS + qb0 + w * 16 + n16;
  for (int db = 0; db < 4; db++) {
    u16x4 pk = { f2bf(o[db][0] * inv), f2bf(o[db][1] * inv),
                 f2bf(o[db][2] * inv), f2bf(o[db][3] * inv) };
    *(u16x4*)&y[tok * EE + h * DHH + db * 16 + quad * 4] = pk;
  }
}

// ---------------------------------------------------------------- proj GEMM (m97-style, 128x64)
__global__ __launch_bounds__(256) void gemm_proj(
    const u16* __restrict__ A, const u16* __restrict__ Bt, float* __restrict__ out) {
  __shared__ __align__(16) u16 As[128 * 64];
  __shared__ __align__(16) u16 Bs[64 * 64];
  const int t = threadIdx.x, w = t >> 6, lane = t & 63;
  const int n16 = lane & 15, quad = lane >> 4;
  const int m0 = blockIdx.y * 128, n0 = blockIdx.x * 64;
  const int mr = lane & 7, kc8 = (lane >> 3) * 8;

  const u16* gA = A + (m0 + w * 32 + mr) * 640 + kc8;
  const u16* gB = Bt + (n0 + w * 16 + mr) * 640 + kc8;
  u16* lA = &As[w * 4 * 512];
  u16* lB = &Bs[w * 2 * 512];

  f32x4 acc[2][4];
  for (int i = 0; i < 2; i++)
    for (int j = 0; j < 4; j++) acc[i][j] = f32x4{0.f, 0.f, 0.f, 0.f};

  for (int kt = 0; kt < 10; ++kt) {
    __syncthreads();
    for (int j = 0; j < 4; ++j)
      gll16(gA + j * 8 * 640 + kt * 64, lA + j * 512);
    for (int j = 0; j < 2; ++j)
      gll16(gB + j * 8 * 640 + kt * 64, lB + j * 512);
    __syncthreads();
    for (int ks = 0; ks < 2; ++ks) {
      bf16x8 a[2], b[4];
      for (int mi = 0; mi < 2; mi++) {
        int m = w * 32 + mi * 16 + n16;
        a[mi] = *(const bf16x8*)&As[(m >> 3) * 512 + (ks * 4 + quad) * 64 + (m & 7) * 8];
      }
      for (int ni = 0; ni < 4; ni++) {
        int n = ni * 16 + n16;
        b[ni] = *(const bf16x8*)&Bs[(n >> 3) * 512 + (ks * 4 + quad) * 64 + (n & 7) * 8];
      }
      for (int mi = 0; mi < 2; mi++)
        for (int ni = 0; ni < 4; ni++)
          acc[mi][ni] = __builtin_amdgcn_mfma_f32_16x16x32_bf16(a[mi], b[ni], acc[mi][ni], 0, 0, 0);
    }
  }

  for (int ni = 0; ni < 4; ni++) {
    int col = n0 + ni * 16 + n16;
    for (int mi = 0; mi < 2; mi++) {
      int rowb = m0 + w * 32 + mi * 16 + quad * 4;
      f32x4 c = acc[mi][ni];
      for (int r = 0; r < 4; r++) out[(rowb + r) * 640 + col] = c[r];
    }
  }
}

// ---------------------------------------------------------------- launch
extern "C" void kernel_launch(void* const* d_in, const int* in_sizes, int n_in,
                              void* d_out, int out_size, void* d_ws, size_t ws_size,
                              hipStream_t stream) {
  const float* x     = (const float*)d_in[0];   // [4,2048,640]
  const float* wqkv  = (const float*)d_in[1];   // [1920,640]
  const float* wproj = (const float*)d_in[2];   // [640,640]
  float* out = (float*)d_out;

  char* ws = (char*)d_ws;
  u16* xb     = (u16*)(ws + 0);            // 10,485,760 B
  u16* wqkvb  = (u16*)(ws + 10485760);     //  2,457,600 B
  u16* wprojb = (u16*)(ws + 12943360);     //    819,200 B
  u16* qTb    = (u16*)(ws + 13762560);     // 10,485,760 B  [bh][d][s], pre-scaled
  u16* kbuf   = (u16*)(ws + 24248320);     // 10,485,760 B  [bh][s][d]
  u16* vtb    = (u16*)(ws + 34734080);     // 10,485,760 B  [bh][d][s]
  u16* ybuf   = (u16*)(ws + 45219840);     // 10,485,760 B  [tok][e]

  convert_all<<<6720, 256, 0, stream>>>(x, wqkv, wproj, xb, wqkvb, wprojb);
  gemm_qkv<<<dim3(15, 64), 256, 0, stream>>>(xb, wqkvb, qTb, kbuf, vtb);
  attn_kernel<<<dim3(40, 32), 256, 0, stream>>>(qTb, kbuf, vtb, ybuf);
  gemm_proj<<<dim3(10, 64), 256, 0, stream>>>(ybuf, wprojb, out);
}